// Round 18
// baseline (177.898 us; speedup 1.0000x reference)
//
#include <hip/hip_runtime.h>

// GraphSAGE 'pool' aggregator, 3 layers, N=50000, E=1.25M, D=64.
// relu(h[src] @ Wp + b) == relu(h @ Wp + b)[src] -> node-level GEMM + gather.
// z >= 0 after relu, so segment_max with 0-init == where(isfinite(.),.,0).
// All intermediates bf16 (monotone rounding -> max exact in bf16 space).
// GEMMs: v_mfma_f32_16x16x32_bf16, A-frags direct from global, B-frags from
// pre-formatted weight buffer.
// CSR build: two-level counting sort at 512 thr/block (round-15 occupancy fix).
// Round-18: agg_max at 4 nodes/wave (4 independent gather chains; round-17's
// 2-node gave -7us, chain still latency-bound). Stores from slot-groups 0-3
// in parallel.
// Round-14 lesson: grid.sync() ~250us on MI355X -- no cooperative kernels.
// Round-6/16 lesson: never narrow the edge-gather's wave parallelism.

#define NN 50000
#define NE 1250000
#define DD 64

#define BSH 7                 // 128 dst nodes per bucket
#define NB1 391               // ceil(50000 / 128)
#define CHUNK 2048            // edges per block in coarse passes
#define NBLK1 611             // ceil(NE / CHUNK)

#define GEMM_BLOCKS 782       // 64-row tiles (4 waves x 16 rows)
#define CAST_BLOCKS 400
#define NMAT 9                // Wp0..2, Ws0..2, Wn0..2 -> fragment buffer

using bf16x8 = __attribute__((ext_vector_type(8))) short;
using f32x4  = __attribute__((ext_vector_type(4))) float;

__device__ __forceinline__ f32x4 mfma16(bf16x8 a, bf16x8 b, f32x4 c) {
    return __builtin_amdgcn_mfma_f32_16x16x32_bf16(a, b, c, 0, 0, 0);
}

__device__ __forceinline__ unsigned int f32_to_bf16_bits(float f) {
    unsigned int u = __float_as_uint(f);
    return (u + 0x7FFFu + ((u >> 16) & 1u)) >> 16;   // RNE
}
__device__ __forceinline__ unsigned int pack2bf16(float a, float b) {
    return f32_to_bf16_bits(a) | (f32_to_bf16_bits(b) << 16);
}
__device__ __forceinline__ unsigned int pkmax(unsigned int a, unsigned int b) {
    unsigned int r;
    asm("v_pk_max_u16 %0, %1, %2" : "=v"(r) : "v"(a), "v"(b));
    return r;
}

__device__ __forceinline__ void load_A(const unsigned short* __restrict__ h,
                                       int row0, int lane, bf16x8& a0, bf16x8& a1) {
    int r = row0 + (lane & 15);
    int kk = (lane >> 4) * 8;
    a0 = bf16x8{0, 0, 0, 0, 0, 0, 0, 0};
    a1 = a0;
    if (r < NN) {
        a0 = *(const bf16x8*)(h + (size_t)r * DD + kk);
        a1 = *(const bf16x8*)(h + (size_t)r * DD + kk + 32);
    }
}

// ---------------- fat kernel 1: edge histogram | in_feat cast | W reformat ----------------

__global__ __launch_bounds__(256) void fat1(const int* __restrict__ dst,
                                            int* __restrict__ H,
                                            const float* __restrict__ in_feat,
                                            unsigned short* __restrict__ h0,
                                            const float* __restrict__ Wp,
                                            const float* __restrict__ Ws,
                                            const float* __restrict__ Wn,
                                            unsigned short* __restrict__ wb) {
    __shared__ int hist[NB1];
    int tid = threadIdx.x;
    int bx = blockIdx.x;
    if (bx < NBLK1) {
        for (int i = tid; i < NB1; i += 256) hist[i] = 0;
        __syncthreads();
        int base = bx * CHUNK;
        int end = min(base + CHUNK, NE);
        for (int i = base + tid; i < end; i += 256) atomicAdd(&hist[dst[i] >> BSH], 1);
        __syncthreads();
        for (int k = tid; k < NB1; k += 256) H[k * NBLK1 + bx] = hist[k];
        return;
    }
    if (bx < NBLK1 + CAST_BLOCKS) {
        const float4* inv = (const float4*)in_feat;
        uint4* ov = (uint4*)h0;
        int t = (bx - NBLK1) * 256 + tid;
        for (int u = t; u < (NN * DD) / 8; u += CAST_BLOCKS * 256) {
            float4 f0 = inv[u * 2], f1 = inv[u * 2 + 1];
            uint4 o;
            o.x = pack2bf16(f0.x, f0.y);
            o.y = pack2bf16(f0.z, f0.w);
            o.z = pack2bf16(f1.x, f1.y);
            o.w = pack2bf16(f1.z, f1.w);
            ov[u] = o;
        }
        return;
    }
    int m = bx - NBLK1 - CAST_BLOCKS;   // 0..8
    const float* srcW = (m < 3) ? (Wp + (size_t)m * DD * DD)
                    : (m < 6) ? (Ws + (size_t)(m - 3) * DD * DD)
                              : (Wn + (size_t)(m - 6) * DD * DD);
    unsigned short* dstW = wb + (size_t)m * 512 * 8;
    for (int idx = tid; idx < 512; idx += 256) {
        int lane = idx & 63, cc = (idx >> 6) & 3, s = idx >> 8;
        int col = cc * 16 + (lane & 15);
        int kb = s * 32 + ((lane >> 4) << 3);
#pragma unroll
        for (int j = 0; j < 8; ++j)
            dstW[idx * 8 + j] = (unsigned short)f32_to_bf16_bits(srcW[(kb + j) * DD + col]);
    }
}

// ---------------- fat kernel 2: rowsum+scan (ticket) | pool0 MFMA ----------------

__global__ __launch_bounds__(256) void fat2(const int* __restrict__ H,
                                            int* __restrict__ rowsum,
                                            int* __restrict__ colbase,
                                            int* __restrict__ ticket,
                                            const unsigned short* __restrict__ h0,
                                            const unsigned short* __restrict__ wb,
                                            const float* __restrict__ bp,
                                            unsigned short* __restrict__ z) {
    __shared__ int s[256];
    __shared__ int isLast;
    int tid = threadIdx.x;
    int bx = blockIdx.x;
    if (bx < NB1) {
        int k = bx;
        int v = 0;
        for (int b = tid; b < NBLK1; b += 256) v += H[k * NBLK1 + b];
        s[tid] = v;
        __syncthreads();
        for (int o = 128; o > 0; o >>= 1) {
            if (tid < o) s[tid] += s[tid + o];
            __syncthreads();
        }
        if (tid == 0) {
            atomicExch(&rowsum[k], s[0]);
            __threadfence();
            isLast = (atomicAdd(ticket, 1) == NB1 - 1);
        }
        __syncthreads();
        if (!isLast) return;
        if (tid < 64) {
            int running = 0;
            for (int b0 = 0; b0 < NB1; b0 += 64) {
                int idx = b0 + tid;
                int val = (idx < NB1) ? atomicAdd(&rowsum[idx], 0) : 0;
                int incl = val;
#pragma unroll
                for (int o = 1; o < 64; o <<= 1) {
                    int up = __shfl_up(incl, o);
                    if (tid >= o) incl += up;
                }
                if (idx < NB1) colbase[idx] = running + (incl - val);
                running += __shfl(incl, 63);
            }
            if (tid == 0) colbase[NB1] = running;
        }
        return;
    }
    // pool0: z = relu(h0 @ Wp0 + bp0) -> bf16
    int lane = tid & 63;
    int row0 = (bx - NB1) * 64 + (tid >> 6) * 16;
    bf16x8 a0, a1;
    load_A(h0, row0, lane, a0, a1);
    const bf16x8* WB = (const bf16x8*)wb;   // matrix 0 = Wp0
    f32x4 acc[4];
#pragma unroll
    for (int c = 0; c < 4; ++c) {
        float bv = bp[c * 16 + (lane & 15)];
        acc[c] = f32x4{bv, bv, bv, bv};
        acc[c] = mfma16(a0, WB[(0 * 4 + c) * 64 + lane], acc[c]);
        acc[c] = mfma16(a1, WB[(1 * 4 + c) * 64 + lane], acc[c]);
    }
    int rbase = row0 + (lane >> 4) * 4;
#pragma unroll
    for (int reg = 0; reg < 4; ++reg) {
        int row = rbase + reg;
        if (row < NN) {
#pragma unroll
            for (int c = 0; c < 4; ++c)
                z[(size_t)row * DD + c * 16 + (lane & 15)] =
                    (unsigned short)f32_to_bf16_bits(fmaxf(acc[c][reg], 0.f));
        }
    }
}

// ---------------- CSR rest ----------------

__global__ __launch_bounds__(256) void k3_offsets(int* __restrict__ H,
                                                  const int* __restrict__ colbase) {
    int wid = (blockIdx.x * blockDim.x + threadIdx.x) >> 6;
    int lane = threadIdx.x & 63;
    if (wid >= NB1) return;
    int running = colbase[wid];
    int* row = H + wid * NBLK1;
    for (int b0 = 0; b0 < NBLK1; b0 += 64) {
        int idx = b0 + lane;
        int v = (idx < NBLK1) ? row[idx] : 0;
        int incl = v;
#pragma unroll
        for (int o = 1; o < 64; o <<= 1) {
            int up = __shfl_up(incl, o);
            if (lane >= o) incl += up;
        }
        if (idx < NBLK1) row[idx] = running + (incl - v);
        running += __shfl(incl, 63);
    }
}

// p1_scatter: 512 threads. LDS counting-sort of each 2048-edge chunk, then
// coalesced run write-out (binary search for bucket). Block-wide scan.
__global__ __launch_bounds__(512) void p1_scatter(const int* __restrict__ dst,
                                                  const int* __restrict__ src,
                                                  const int* __restrict__ H,
                                                  int* __restrict__ pairs, int e) {
    __shared__ int off[NB1];
    __shared__ int hcnt[NB1];
    __shared__ int cursor[NB1];
    __shared__ int lbase[NB1 + 1];
    __shared__ int sorted[CHUNK];
    __shared__ int sbuf[2][512];
    int tid = threadIdx.x, bx = blockIdx.x;
    for (int i = tid; i < NB1; i += 512) {
        off[i] = H[i * NBLK1 + bx];
        hcnt[i] = 0;
        cursor[i] = 0;
    }
    __syncthreads();
    int base = bx * CHUNK;
    int end = min(base + CHUNK, e);
    int L = end - base;
    for (int i = base + tid; i < end; i += 512) atomicAdd(&hcnt[dst[i] >> BSH], 1);
    __syncthreads();
    int myv = (tid < NB1) ? hcnt[tid] : 0;
    sbuf[0][tid] = myv;
    __syncthreads();
    int cur = 0;
    for (int o = 1; o < 512; o <<= 1) {
        sbuf[cur ^ 1][tid] = sbuf[cur][tid] + ((tid >= o) ? sbuf[cur][tid - o] : 0);
        cur ^= 1;
        __syncthreads();
    }
    if (tid < NB1) lbase[tid] = sbuf[cur][tid] - myv;
    if (tid == 0) lbase[NB1] = L;
    __syncthreads();
    for (int i = base + tid; i < end; i += 512) {
        int d = dst[i];
        int k = d >> BSH;
        int r = atomicAdd(&cursor[k], 1);
        sorted[lbase[k] + r] = ((d & 127) << 16) | src[i];   // src < 65536
    }
    __syncthreads();
    for (int t = tid; t < L; t += 512) {
        int lo = 0, hi = NB1;
        while (hi - lo > 1) {
            int mid = (lo + hi) >> 1;
            if (t >= lbase[mid]) lo = mid; else hi = mid;
        }
        pairs[off[lo] + (t - lbase[lo])] = sorted[t];
    }
}

// p2_bucket: 512 threads. Fine-sort the bucket's contiguous segment in LDS,
// stream edge_src out coalesced.
__global__ __launch_bounds__(512) void p2_bucket(const int* __restrict__ pairs,
                                                 const int* __restrict__ colbase,
                                                 int* __restrict__ rowptr,
                                                 unsigned short* __restrict__ edge_src) {
    __shared__ int cnt[128];
    __shared__ int base2[128];
    __shared__ int cur2[128];
    __shared__ int sbuf[2][128];
    __shared__ unsigned short stage[8192];
    int k = blockIdx.x;
    int tid = threadIdx.x;
    int beg = colbase[k], end = colbase[k + 1];
    int len = end - beg;
    if (tid < 128) { cnt[tid] = 0; cur2[tid] = 0; }
    __syncthreads();
    for (int i = beg + tid; i < end; i += 512) atomicAdd(&cnt[pairs[i] >> 16], 1);
    __syncthreads();
    if (tid < 128) sbuf[0][tid] = cnt[tid];
    __syncthreads();
    int cur = 0;
    for (int o = 1; o < 128; o <<= 1) {
        if (tid < 128) sbuf[cur ^ 1][tid] = sbuf[cur][tid] + ((tid >= o) ? sbuf[cur][tid - o] : 0);
        cur ^= 1;
        __syncthreads();
    }
    if (tid < 128) {
        int excl = sbuf[cur][tid] - cnt[tid];
        base2[tid] = excl;
        int node = (k << BSH) + tid;
        if (node < NN) rowptr[node] = beg + excl;
    }
    __syncthreads();
    if (len <= 8192) {
        for (int i = beg + tid; i < end; i += 512) {
            int p = pairs[i];
            int r = atomicAdd(&cur2[p >> 16], 1);
            stage[base2[p >> 16] + r] = (unsigned short)(p & 0xFFFF);
        }
        __syncthreads();
        for (int t = tid; t < len; t += 512) edge_src[beg + t] = stage[t];
    } else {  // robustness fallback (statistically unreachable: mean 3200, 8192 > 80 sd)
        for (int i = beg + tid; i < end; i += 512) {
            int p = pairs[i];
            int r = atomicAdd(&cur2[p >> 16], 1);
            edge_src[beg + base2[p >> 16] + r] = (unsigned short)(p & 0xFFFF);
        }
    }
    if (k == 0 && tid == 0) rowptr[NN] = NE;
}

// ---------------- fused out+pool (MFMA) ----------------

__global__ __launch_bounds__(256) void gemm_fused_mfma(const unsigned short* __restrict__ h,
                                                       const unsigned short* __restrict__ agg,
                                                       const unsigned short* __restrict__ wbs,
                                                       const unsigned short* __restrict__ wbn,
                                                       const unsigned short* __restrict__ wbp,
                                                       const float* __restrict__ b,
                                                       const float* __restrict__ bp,
                                                       unsigned short* __restrict__ hn_out,
                                                       unsigned short* __restrict__ z) {
    __shared__ unsigned short hnl[4][16 * 72];   // per-wave C->A redistribution tile
    int tid = threadIdx.x;
    int w = tid >> 6, lane = tid & 63;
    int row0 = blockIdx.x * 64 + w * 16;
    bf16x8 ah0, ah1, ag0, ag1;
    load_A(h, row0, lane, ah0, ah1);
    load_A(agg, row0, lane, ag0, ag1);
    const bf16x8* WS = (const bf16x8*)wbs;
    const bf16x8* WN = (const bf16x8*)wbn;
    const bf16x8* WP = (const bf16x8*)wbp;
    f32x4 acc[4];
#pragma unroll
    for (int c = 0; c < 4; ++c) {
        float bv = b[c * 16 + (lane & 15)];
        acc[c] = f32x4{bv, bv, bv, bv};
        acc[c] = mfma16(ah0, WS[(0 * 4 + c) * 64 + lane], acc[c]);
        acc[c] = mfma16(ah1, WS[(1 * 4 + c) * 64 + lane], acc[c]);
        acc[c] = mfma16(ag0, WN[(0 * 4 + c) * 64 + lane], acc[c]);
        acc[c] = mfma16(ag1, WN[(1 * 4 + c) * 64 + lane], acc[c]);
    }
    int rloc = (lane >> 4) * 4;
    int rbase = row0 + rloc;
#pragma unroll
    for (int reg = 0; reg < 4; ++reg) {
        int row = rbase + reg;
#pragma unroll
        for (int c = 0; c < 4; ++c) {
            unsigned short us =
                (unsigned short)f32_to_bf16_bits(fmaxf(acc[c][reg], 0.f));
            hnl[w][(rloc + reg) * 72 + c * 16 + (lane & 15)] = us;
            if (row < NN) hn_out[(size_t)row * DD + c * 16 + (lane & 15)] = us;
        }
    }
    int kk = (lane >> 4) * 8;
    bf16x8 p0 = *(const bf16x8*)&hnl[w][(lane & 15) * 72 + kk];
    bf16x8 p1 = *(const bf16x8*)&hnl[w][(lane & 15) * 72 + kk + 32];
    f32x4 acc2[4];
#pragma unroll
    for (int c = 0; c < 4; ++c) {
        float bv = bp[c * 16 + (lane & 15)];
        acc2[c] = f32x4{bv, bv, bv, bv};
        acc2[c] = mfma16(p0, WP[(0 * 4 + c) * 64 + lane], acc2[c]);
        acc2[c] = mfma16(p1, WP[(1 * 4 + c) * 64 + lane], acc2[c]);
    }
#pragma unroll
    for (int reg = 0; reg < 4; ++reg) {
        int row = rbase + reg;
        if (row < NN) {
#pragma unroll
            for (int c = 0; c < 4; ++c)
                z[(size_t)row * DD + c * 16 + (lane & 15)] =
                    (unsigned short)f32_to_bf16_bits(fmaxf(acc2[c][reg], 0.f));
        }
    }
}

// final layer: out(f32) = h @ Ws + agg @ Wn + b
__global__ __launch_bounds__(256) void gemm_final_mfma(const unsigned short* __restrict__ h,
                                                       const unsigned short* __restrict__ agg,
                                                       const unsigned short* __restrict__ wbs,
                                                       const unsigned short* __restrict__ wbn,
                                                       const float* __restrict__ b,
                                                       float* __restrict__ out) {
    int tid = threadIdx.x;
    int lane = tid & 63;
    int row0 = blockIdx.x * 64 + (tid >> 6) * 16;
    bf16x8 ah0, ah1, ag0, ag1;
    load_A(h, row0, lane, ah0, ah1);
    load_A(agg, row0, lane, ag0, ag1);
    const bf16x8* WS = (const bf16x8*)wbs;
    const bf16x8* WN = (const bf16x8*)wbn;
    f32x4 acc[4];
#pragma unroll
    for (int c = 0; c < 4; ++c) {
        float bv = b[c * 16 + (lane & 15)];
        acc[c] = f32x4{bv, bv, bv, bv};
        acc[c] = mfma16(ah0, WS[(0 * 4 + c) * 64 + lane], acc[c]);
        acc[c] = mfma16(ah1, WS[(1 * 4 + c) * 64 + lane], acc[c]);
        acc[c] = mfma16(ag0, WN[(0 * 4 + c) * 64 + lane], acc[c]);
        acc[c] = mfma16(ag1, WN[(1 * 4 + c) * 64 + lane], acc[c]);
    }
    int rbase = row0 + (lane >> 4) * 4;
#pragma unroll
    for (int reg = 0; reg < 4; ++reg) {
        int row = rbase + reg;
        if (row < NN) {
#pragma unroll
            for (int c = 0; c < 4; ++c)
                out[(size_t)row * DD + c * 16 + (lane & 15)] = acc[c][reg];
        }
    }
}

// ---------------- Aggregation: grid-stride, 4 nodes per wave (MLP x4) ----------------

__global__ __launch_bounds__(256) void agg_max(const unsigned short* __restrict__ z,
                                               const int* __restrict__ rowptr,
                                               const unsigned short* __restrict__ edge_src,
                                               unsigned short* __restrict__ agg, int n) {
    int wslot = __builtin_amdgcn_readfirstlane((int)((blockIdx.x * blockDim.x + threadIdx.x) >> 6));
    int nslots = (gridDim.x * blockDim.x) >> 6;
    int lane = threadIdx.x & 63;
    int eg = lane >> 3;            // edge slot (0..7)
    int fo = (lane & 7) * 8;       // feature offset (8 bf16 = 16B per lane)
    for (int nb = wslot * 4; nb < n; nb += nslots * 4) {
        int n0 = nb, n1 = nb + 1, n2 = nb + 2, n3 = nb + 3;
        int e0 = rowptr[n0] + eg, d0 = rowptr[n0 + 1];
        int e1 = 0, d1 = 0, e2 = 0, d2 = 0, e3 = 0, d3 = 0;
        if (n1 < n) { e1 = rowptr[n1] + eg; d1 = rowptr[n1 + 1]; }
        if (n2 < n) { e2 = rowptr[n2] + eg; d2 = rowptr[n2 + 1]; }
        if (n3 < n) { e3 = rowptr[n3] + eg; d3 = rowptr[n3 + 1]; }
        unsigned int a0 = 0, a1 = 0, a2 = 0, a3 = 0;   // node0
        unsigned int b0 = 0, b1 = 0, b2 = 0, b3 = 0;   // node1
        unsigned int c0 = 0, c1 = 0, c2 = 0, c3 = 0;   // node2
        unsigned int g0 = 0, g1 = 0, g2 = 0, g3 = 0;   // node3
        // four independent gather chains kept in flight via predication
        while ((e0 < d0) || (e1 < d1) || (e2 < d2) || (e3 < d3)) {
            if (e0 < d0) {
                int s = edge_src[e0];
                uint4 v = *(const uint4*)(z + (size_t)s * DD + fo);
                a0 = pkmax(a0, v.x); a1 = pkmax(a1, v.y);
                a2 = pkmax(a2, v.z); a3 = pkmax(a3, v.w);
                e0 += 8;
            }
            if (e1 < d1) {
                int s = edge_src[e1];
                uint4 v = *(const uint4*)(z + (size_t)s * DD + fo);
                b0 = pkmax(b0, v.x); b1 = pkmax(b1, v.y);
                b2 = pkmax(b2, v.z); b3 = pkmax(b3, v.w);
                e1 += 8;
            }
            if (e2 < d2) {
                int s = edge_src[e2];
                uint4 v = *(const uint4*)(z + (size_t)s * DD + fo);
                c0 = pkmax(c0, v.x); c1 = pkmax(c1, v.y);
                c2 = pkmax(c2, v.z); c3 = pkmax(c3, v.w);
                e2 += 8;
            }
            if (e3 < d3) {
                int s = edge_src[e3];
                uint4 v = *(const uint4*)(z + (size_t)s * DD + fo);
                g0 = pkmax(g0, v.x); g1 = pkmax(g1, v.y);
                g2 = pkmax(g2, v.z); g3 = pkmax(g3, v.w);
                e3 += 8;
            }
        }
        // reduce across the 8 edge slots (xor 8, 16, 32 in lane space)
#pragma unroll
        for (int o = 8; o < 64; o <<= 1) {
            a0 = pkmax(a0, (unsigned int)__shfl_xor((int)a0, o));
            a1 = pkmax(a1, (unsigned int)__shfl_xor((int)a1, o));
            a2 = pkmax(a2, (unsigned int)__shfl_xor((int)a2, o));
            a3 = pkmax(a3, (unsigned int)__shfl_xor((int)a3, o));
            b0 = pkmax(b0, (unsigned int)__shfl_xor((int)b0, o));
            b1 = pkmax(b1, (unsigned int)__shfl_xor((int)b1, o));
            b2 = pkmax(b2, (unsigned int)__shfl_xor((int)b2, o));
            b3 = pkmax(b3, (unsigned int)__shfl_xor((int)b3, o));
            c0 = pkmax(c0, (unsigned int)__shfl_xor((int)c0, o));
            c1 = pkmax(c1, (unsigned int)__shfl_xor((int)c1, o));
            c2 = pkmax(c2, (unsigned int)__shfl_xor((int)c2, o));
            c3 = pkmax(c3, (unsigned int)__shfl_xor((int)c3, o));
            g0 = pkmax(g0, (unsigned int)__shfl_xor((int)g0, o));
            g1 = pkmax(g1, (unsigned int)__shfl_xor((int)g1, o));
            g2 = pkmax(g2, (unsigned int)__shfl_xor((int)g2, o));
            g3 = pkmax(g3, (unsigned int)__shfl_xor((int)g3, o));
        }
        if (eg == 0) {
            uint4 o;
            o.x = a0; o.y = a1; o.z = a2; o.w = a3;
            *(uint4*)(agg + (size_t)n0 * DD + fo) = o;
        } else if (eg == 1 && n1 < n) {
            uint4 o;
            o.x = b0; o.y = b1; o.z = b2; o.w = b3;
            *(uint4*)(agg + (size_t)n1 * DD + fo) = o;
        } else if (eg == 2 && n2 < n) {
            uint4 o;
            o.x = c0; o.y = c1; o.z = c2; o.w = c3;
            *(uint4*)(agg + (size_t)n2 * DD + fo) = o;
        } else if (eg == 3 && n3 < n) {
            uint4 o;
            o.x = g0; o.y = g1; o.z = g2; o.w = g3;
            *(uint4*)(agg + (size_t)n3 * DD + fo) = o;
        }
    }
}

// ---------------- Orchestration ----------------

extern "C" void kernel_launch(void* const* d_in, const int* in_sizes, int n_in,
                              void* d_out, int out_size, void* d_ws, size_t ws_size,
                              hipStream_t stream) {
    const float* in_feat = (const float*)d_in[0];
    const int* src = (const int*)d_in[1];
    const int* dst = (const int*)d_in[2];
    const float* W_pool = (const float*)d_in[3];
    const float* b_pool = (const float*)d_in[4];
    const float* W_self = (const float*)d_in[5];
    const float* W_neigh = (const float*)d_in[6];
    const float* bias = (const float*)d_in[7];
    float* out = (float*)d_out;

    char* ws = (char*)d_ws;
    size_t off = 0;
    auto alloc = [&](size_t bytes) -> void* {
        void* p = (void*)(ws + off);
        off += (bytes + 255) & ~(size_t)255;
        return p;
    };
    int* rowptr              = (int*)alloc((NN + 1) * sizeof(int));
    int* H                   = (int*)alloc((size_t)NB1 * NBLK1 * sizeof(int));
    int* rowsum              = (int*)alloc(NB1 * sizeof(int));
    int* colbase             = (int*)alloc((NB1 + 1) * sizeof(int));
    int* ticket              = (int*)alloc(sizeof(int));
    unsigned short* edge_src = (unsigned short*)alloc((size_t)NE * sizeof(unsigned short));
    unsigned short* z        = (unsigned short*)alloc((size_t)NN * DD * sizeof(unsigned short));
    unsigned short* agg      = (unsigned short*)alloc((size_t)NN * DD * sizeof(unsigned short));
    unsigned short* h0       = (unsigned short*)alloc((size_t)NN * DD * sizeof(unsigned short));
    unsigned short* h1       = (unsigned short*)alloc((size_t)NN * DD * sizeof(unsigned short));
    unsigned short* h2       = (unsigned short*)alloc((size_t)NN * DD * sizeof(unsigned short));
    unsigned short* wb       = (unsigned short*)alloc((size_t)NMAT * 512 * 8 * sizeof(unsigned short));
    int* pairs               = (int*)alloc((size_t)NE * sizeof(int));
    (void)ws_size; (void)in_sizes; (void)n_in; (void)out_size;

    hipMemsetAsync(ticket, 0, sizeof(int), stream);

    auto WBp = [&](int l) { return wb + (size_t)(0 + l) * 4096; };
    auto WBs = [&](int l) { return wb + (size_t)(3 + l) * 4096; };
    auto WBn = [&](int l) { return wb + (size_t)(6 + l) * 4096; };

    // ---- fat1: edge histogram | in_feat cast | weight reformat ----
    fat1<<<NBLK1 + CAST_BLOCKS + NMAT, 256, 0, stream>>>(
        dst, H, in_feat, h0, W_pool, W_self, W_neigh, wb);
    // ---- fat2: rowsum+scan | pool0 MFMA ----
    fat2<<<NB1 + GEMM_BLOCKS, 256, 0, stream>>>(
        H, rowsum, colbase, ticket, h0, wb, b_pool, z);
    // ---- CSR rest (p1/p2 at 512 threads for occupancy in barrier phases) ----
    k3_offsets<<<(NB1 * 64 + 255) / 256, 256, 0, stream>>>(H, colbase);
    p1_scatter<<<NBLK1, 512, 0, stream>>>(dst, src, H, pairs, NE);
    p2_bucket<<<NB1, 512, 0, stream>>>(pairs, colbase, rowptr, edge_src);

    // ---- 3 layers ----
    agg_max<<<2048, 256, 0, stream>>>(z, rowptr, edge_src, agg, NN);
    gemm_fused_mfma<<<GEMM_BLOCKS, 256, 0, stream>>>(
        h0, agg, WBs(0), WBn(0), WBp(1), bias, b_pool + DD, h1, z);
    agg_max<<<2048, 256, 0, stream>>>(z, rowptr, edge_src, agg, NN);
    gemm_fused_mfma<<<GEMM_BLOCKS, 256, 0, stream>>>(
        h1, agg, WBs(1), WBn(1), WBp(2), bias + DD, b_pool + 2 * DD, h2, z);
    agg_max<<<2048, 256, 0, stream>>>(z, rowptr, edge_src, agg, NN);
    gemm_final_mfma<<<GEMM_BLOCKS, 256, 0, stream>>>(
        h2, agg, WBs(2), WBn(2), bias + 2 * DD, out);
}

// Round 19
// 158.985 us; speedup vs baseline: 1.1190x; 1.1190x over previous
//
#include <hip/hip_runtime.h>

// GraphSAGE 'pool' aggregator, 3 layers, N=50000, E=1.25M, D=64.
// relu(h[src] @ Wp + b) == relu(h @ Wp + b)[src] -> node-level GEMM + gather.
// z >= 0 after relu, so segment_max with 0-init == where(isfinite(.),.,0).
// All intermediates bf16 (monotone rounding -> max exact in bf16 space).
// GEMMs: v_mfma_f32_16x16x32_bf16, A-frags direct from global, B-frags from
// pre-formatted weight buffer.
// CSR build: two-level counting sort at 512 thr/block (round-15 occupancy fix).
// agg_max: 2 nodes/wave, STRAIGHT-LINE interleaved dual gather chains
// (round-17 best; round-18's predicated 4-chain loop regressed -- exec-mask
// branching serializes the loads. Interleave straight-line only.)
// Round-14 lesson: grid.sync() ~250us on MI355X -- no cooperative kernels.
// Round-6/16 lesson: never narrow the edge-gather's wave parallelism.

#define NN 50000
#define NE 1250000
#define DD 64

#define BSH 7                 // 128 dst nodes per bucket
#define NB1 391               // ceil(50000 / 128)
#define CHUNK 2048            // edges per block in coarse passes
#define NBLK1 611             // ceil(NE / CHUNK)

#define GEMM_BLOCKS 782       // 64-row tiles (4 waves x 16 rows)
#define CAST_BLOCKS 400
#define NMAT 9                // Wp0..2, Ws0..2, Wn0..2 -> fragment buffer

using bf16x8 = __attribute__((ext_vector_type(8))) short;
using f32x4  = __attribute__((ext_vector_type(4))) float;

__device__ __forceinline__ f32x4 mfma16(bf16x8 a, bf16x8 b, f32x4 c) {
    return __builtin_amdgcn_mfma_f32_16x16x32_bf16(a, b, c, 0, 0, 0);
}

__device__ __forceinline__ unsigned int f32_to_bf16_bits(float f) {
    unsigned int u = __float_as_uint(f);
    return (u + 0x7FFFu + ((u >> 16) & 1u)) >> 16;   // RNE
}
__device__ __forceinline__ unsigned int pack2bf16(float a, float b) {
    return f32_to_bf16_bits(a) | (f32_to_bf16_bits(b) << 16);
}
__device__ __forceinline__ unsigned int pkmax(unsigned int a, unsigned int b) {
    unsigned int r;
    asm("v_pk_max_u16 %0, %1, %2" : "=v"(r) : "v"(a), "v"(b));
    return r;
}

__device__ __forceinline__ void load_A(const unsigned short* __restrict__ h,
                                       int row0, int lane, bf16x8& a0, bf16x8& a1) {
    int r = row0 + (lane & 15);
    int kk = (lane >> 4) * 8;
    a0 = bf16x8{0, 0, 0, 0, 0, 0, 0, 0};
    a1 = a0;
    if (r < NN) {
        a0 = *(const bf16x8*)(h + (size_t)r * DD + kk);
        a1 = *(const bf16x8*)(h + (size_t)r * DD + kk + 32);
    }
}

// ---------------- fat kernel 1: edge histogram | in_feat cast | W reformat ----------------

__global__ __launch_bounds__(256) void fat1(const int* __restrict__ dst,
                                            int* __restrict__ H,
                                            const float* __restrict__ in_feat,
                                            unsigned short* __restrict__ h0,
                                            const float* __restrict__ Wp,
                                            const float* __restrict__ Ws,
                                            const float* __restrict__ Wn,
                                            unsigned short* __restrict__ wb) {
    __shared__ int hist[NB1];
    int tid = threadIdx.x;
    int bx = blockIdx.x;
    if (bx < NBLK1) {
        for (int i = tid; i < NB1; i += 256) hist[i] = 0;
        __syncthreads();
        int base = bx * CHUNK;
        int end = min(base + CHUNK, NE);
        for (int i = base + tid; i < end; i += 256) atomicAdd(&hist[dst[i] >> BSH], 1);
        __syncthreads();
        for (int k = tid; k < NB1; k += 256) H[k * NBLK1 + bx] = hist[k];
        return;
    }
    if (bx < NBLK1 + CAST_BLOCKS) {
        const float4* inv = (const float4*)in_feat;
        uint4* ov = (uint4*)h0;
        int t = (bx - NBLK1) * 256 + tid;
        for (int u = t; u < (NN * DD) / 8; u += CAST_BLOCKS * 256) {
            float4 f0 = inv[u * 2], f1 = inv[u * 2 + 1];
            uint4 o;
            o.x = pack2bf16(f0.x, f0.y);
            o.y = pack2bf16(f0.z, f0.w);
            o.z = pack2bf16(f1.x, f1.y);
            o.w = pack2bf16(f1.z, f1.w);
            ov[u] = o;
        }
        return;
    }
    int m = bx - NBLK1 - CAST_BLOCKS;   // 0..8
    const float* srcW = (m < 3) ? (Wp + (size_t)m * DD * DD)
                    : (m < 6) ? (Ws + (size_t)(m - 3) * DD * DD)
                              : (Wn + (size_t)(m - 6) * DD * DD);
    unsigned short* dstW = wb + (size_t)m * 512 * 8;
    for (int idx = tid; idx < 512; idx += 256) {
        int lane = idx & 63, cc = (idx >> 6) & 3, s = idx >> 8;
        int col = cc * 16 + (lane & 15);
        int kb = s * 32 + ((lane >> 4) << 3);
#pragma unroll
        for (int j = 0; j < 8; ++j)
            dstW[idx * 8 + j] = (unsigned short)f32_to_bf16_bits(srcW[(kb + j) * DD + col]);
    }
}

// ---------------- fat kernel 2: rowsum+scan (ticket) | pool0 MFMA ----------------

__global__ __launch_bounds__(256) void fat2(const int* __restrict__ H,
                                            int* __restrict__ rowsum,
                                            int* __restrict__ colbase,
                                            int* __restrict__ ticket,
                                            const unsigned short* __restrict__ h0,
                                            const unsigned short* __restrict__ wb,
                                            const float* __restrict__ bp,
                                            unsigned short* __restrict__ z) {
    __shared__ int s[256];
    __shared__ int isLast;
    int tid = threadIdx.x;
    int bx = blockIdx.x;
    if (bx < NB1) {
        int k = bx;
        int v = 0;
        for (int b = tid; b < NBLK1; b += 256) v += H[k * NBLK1 + b];
        s[tid] = v;
        __syncthreads();
        for (int o = 128; o > 0; o >>= 1) {
            if (tid < o) s[tid] += s[tid + o];
            __syncthreads();
        }
        if (tid == 0) {
            atomicExch(&rowsum[k], s[0]);
            __threadfence();
            isLast = (atomicAdd(ticket, 1) == NB1 - 1);
        }
        __syncthreads();
        if (!isLast) return;
        if (tid < 64) {
            int running = 0;
            for (int b0 = 0; b0 < NB1; b0 += 64) {
                int idx = b0 + tid;
                int val = (idx < NB1) ? atomicAdd(&rowsum[idx], 0) : 0;
                int incl = val;
#pragma unroll
                for (int o = 1; o < 64; o <<= 1) {
                    int up = __shfl_up(incl, o);
                    if (tid >= o) incl += up;
                }
                if (idx < NB1) colbase[idx] = running + (incl - val);
                running += __shfl(incl, 63);
            }
            if (tid == 0) colbase[NB1] = running;
        }
        return;
    }
    // pool0: z = relu(h0 @ Wp0 + bp0) -> bf16
    int lane = tid & 63;
    int row0 = (bx - NB1) * 64 + (tid >> 6) * 16;
    bf16x8 a0, a1;
    load_A(h0, row0, lane, a0, a1);
    const bf16x8* WB = (const bf16x8*)wb;   // matrix 0 = Wp0
    f32x4 acc[4];
#pragma unroll
    for (int c = 0; c < 4; ++c) {
        float bv = bp[c * 16 + (lane & 15)];
        acc[c] = f32x4{bv, bv, bv, bv};
        acc[c] = mfma16(a0, WB[(0 * 4 + c) * 64 + lane], acc[c]);
        acc[c] = mfma16(a1, WB[(1 * 4 + c) * 64 + lane], acc[c]);
    }
    int rbase = row0 + (lane >> 4) * 4;
#pragma unroll
    for (int reg = 0; reg < 4; ++reg) {
        int row = rbase + reg;
        if (row < NN) {
#pragma unroll
            for (int c = 0; c < 4; ++c)
                z[(size_t)row * DD + c * 16 + (lane & 15)] =
                    (unsigned short)f32_to_bf16_bits(fmaxf(acc[c][reg], 0.f));
        }
    }
}

// ---------------- CSR rest ----------------

__global__ __launch_bounds__(256) void k3_offsets(int* __restrict__ H,
                                                  const int* __restrict__ colbase) {
    int wid = (blockIdx.x * blockDim.x + threadIdx.x) >> 6;
    int lane = threadIdx.x & 63;
    if (wid >= NB1) return;
    int running = colbase[wid];
    int* row = H + wid * NBLK1;
    for (int b0 = 0; b0 < NBLK1; b0 += 64) {
        int idx = b0 + lane;
        int v = (idx < NBLK1) ? row[idx] : 0;
        int incl = v;
#pragma unroll
        for (int o = 1; o < 64; o <<= 1) {
            int up = __shfl_up(incl, o);
            if (lane >= o) incl += up;
        }
        if (idx < NBLK1) row[idx] = running + (incl - v);
        running += __shfl(incl, 63);
    }
}

// p1_scatter: 512 threads. LDS counting-sort of each 2048-edge chunk, then
// coalesced run write-out (binary search for bucket). Block-wide scan.
__global__ __launch_bounds__(512) void p1_scatter(const int* __restrict__ dst,
                                                  const int* __restrict__ src,
                                                  const int* __restrict__ H,
                                                  int* __restrict__ pairs, int e) {
    __shared__ int off[NB1];
    __shared__ int hcnt[NB1];
    __shared__ int cursor[NB1];
    __shared__ int lbase[NB1 + 1];
    __shared__ int sorted[CHUNK];
    __shared__ int sbuf[2][512];
    int tid = threadIdx.x, bx = blockIdx.x;
    for (int i = tid; i < NB1; i += 512) {
        off[i] = H[i * NBLK1 + bx];
        hcnt[i] = 0;
        cursor[i] = 0;
    }
    __syncthreads();
    int base = bx * CHUNK;
    int end = min(base + CHUNK, e);
    int L = end - base;
    for (int i = base + tid; i < end; i += 512) atomicAdd(&hcnt[dst[i] >> BSH], 1);
    __syncthreads();
    int myv = (tid < NB1) ? hcnt[tid] : 0;
    sbuf[0][tid] = myv;
    __syncthreads();
    int cur = 0;
    for (int o = 1; o < 512; o <<= 1) {
        sbuf[cur ^ 1][tid] = sbuf[cur][tid] + ((tid >= o) ? sbuf[cur][tid - o] : 0);
        cur ^= 1;
        __syncthreads();
    }
    if (tid < NB1) lbase[tid] = sbuf[cur][tid] - myv;
    if (tid == 0) lbase[NB1] = L;
    __syncthreads();
    for (int i = base + tid; i < end; i += 512) {
        int d = dst[i];
        int k = d >> BSH;
        int r = atomicAdd(&cursor[k], 1);
        sorted[lbase[k] + r] = ((d & 127) << 16) | src[i];   // src < 65536
    }
    __syncthreads();
    for (int t = tid; t < L; t += 512) {
        int lo = 0, hi = NB1;
        while (hi - lo > 1) {
            int mid = (lo + hi) >> 1;
            if (t >= lbase[mid]) lo = mid; else hi = mid;
        }
        pairs[off[lo] + (t - lbase[lo])] = sorted[t];
    }
}

// p2_bucket: 512 threads. Fine-sort the bucket's contiguous segment in LDS,
// stream edge_src out coalesced.
__global__ __launch_bounds__(512) void p2_bucket(const int* __restrict__ pairs,
                                                 const int* __restrict__ colbase,
                                                 int* __restrict__ rowptr,
                                                 unsigned short* __restrict__ edge_src) {
    __shared__ int cnt[128];
    __shared__ int base2[128];
    __shared__ int cur2[128];
    __shared__ int sbuf[2][128];
    __shared__ unsigned short stage[8192];
    int k = blockIdx.x;
    int tid = threadIdx.x;
    int beg = colbase[k], end = colbase[k + 1];
    int len = end - beg;
    if (tid < 128) { cnt[tid] = 0; cur2[tid] = 0; }
    __syncthreads();
    for (int i = beg + tid; i < end; i += 512) atomicAdd(&cnt[pairs[i] >> 16], 1);
    __syncthreads();
    if (tid < 128) sbuf[0][tid] = cnt[tid];
    __syncthreads();
    int cur = 0;
    for (int o = 1; o < 128; o <<= 1) {
        if (tid < 128) sbuf[cur ^ 1][tid] = sbuf[cur][tid] + ((tid >= o) ? sbuf[cur][tid - o] : 0);
        cur ^= 1;
        __syncthreads();
    }
    if (tid < 128) {
        int excl = sbuf[cur][tid] - cnt[tid];
        base2[tid] = excl;
        int node = (k << BSH) + tid;
        if (node < NN) rowptr[node] = beg + excl;
    }
    __syncthreads();
    if (len <= 8192) {
        for (int i = beg + tid; i < end; i += 512) {
            int p = pairs[i];
            int r = atomicAdd(&cur2[p >> 16], 1);
            stage[base2[p >> 16] + r] = (unsigned short)(p & 0xFFFF);
        }
        __syncthreads();
        for (int t = tid; t < len; t += 512) edge_src[beg + t] = stage[t];
    } else {  // robustness fallback (statistically unreachable: mean 3200, 8192 > 80 sd)
        for (int i = beg + tid; i < end; i += 512) {
            int p = pairs[i];
            int r = atomicAdd(&cur2[p >> 16], 1);
            edge_src[beg + base2[p >> 16] + r] = (unsigned short)(p & 0xFFFF);
        }
    }
    if (k == 0 && tid == 0) rowptr[NN] = NE;
}

// ---------------- fused out+pool (MFMA) ----------------

__global__ __launch_bounds__(256) void gemm_fused_mfma(const unsigned short* __restrict__ h,
                                                       const unsigned short* __restrict__ agg,
                                                       const unsigned short* __restrict__ wbs,
                                                       const unsigned short* __restrict__ wbn,
                                                       const unsigned short* __restrict__ wbp,
                                                       const float* __restrict__ b,
                                                       const float* __restrict__ bp,
                                                       unsigned short* __restrict__ hn_out,
                                                       unsigned short* __restrict__ z) {
    __shared__ unsigned short hnl[4][16 * 72];   // per-wave C->A redistribution tile
    int tid = threadIdx.x;
    int w = tid >> 6, lane = tid & 63;
    int row0 = blockIdx.x * 64 + w * 16;
    bf16x8 ah0, ah1, ag0, ag1;
    load_A(h, row0, lane, ah0, ah1);
    load_A(agg, row0, lane, ag0, ag1);
    const bf16x8* WS = (const bf16x8*)wbs;
    const bf16x8* WN = (const bf16x8*)wbn;
    const bf16x8* WP = (const bf16x8*)wbp;
    f32x4 acc[4];
#pragma unroll
    for (int c = 0; c < 4; ++c) {
        float bv = b[c * 16 + (lane & 15)];
        acc[c] = f32x4{bv, bv, bv, bv};
        acc[c] = mfma16(ah0, WS[(0 * 4 + c) * 64 + lane], acc[c]);
        acc[c] = mfma16(ah1, WS[(1 * 4 + c) * 64 + lane], acc[c]);
        acc[c] = mfma16(ag0, WN[(0 * 4 + c) * 64 + lane], acc[c]);
        acc[c] = mfma16(ag1, WN[(1 * 4 + c) * 64 + lane], acc[c]);
    }
    int rloc = (lane >> 4) * 4;
    int rbase = row0 + rloc;
#pragma unroll
    for (int reg = 0; reg < 4; ++reg) {
        int row = rbase + reg;
#pragma unroll
        for (int c = 0; c < 4; ++c) {
            unsigned short us =
                (unsigned short)f32_to_bf16_bits(fmaxf(acc[c][reg], 0.f));
            hnl[w][(rloc + reg) * 72 + c * 16 + (lane & 15)] = us;
            if (row < NN) hn_out[(size_t)row * DD + c * 16 + (lane & 15)] = us;
        }
    }
    int kk = (lane >> 4) * 8;
    bf16x8 p0 = *(const bf16x8*)&hnl[w][(lane & 15) * 72 + kk];
    bf16x8 p1 = *(const bf16x8*)&hnl[w][(lane & 15) * 72 + kk + 32];
    f32x4 acc2[4];
#pragma unroll
    for (int c = 0; c < 4; ++c) {
        float bv = bp[c * 16 + (lane & 15)];
        acc2[c] = f32x4{bv, bv, bv, bv};
        acc2[c] = mfma16(p0, WP[(0 * 4 + c) * 64 + lane], acc2[c]);
        acc2[c] = mfma16(p1, WP[(1 * 4 + c) * 64 + lane], acc2[c]);
    }
#pragma unroll
    for (int reg = 0; reg < 4; ++reg) {
        int row = rbase + reg;
        if (row < NN) {
#pragma unroll
            for (int c = 0; c < 4; ++c)
                z[(size_t)row * DD + c * 16 + (lane & 15)] =
                    (unsigned short)f32_to_bf16_bits(fmaxf(acc2[c][reg], 0.f));
        }
    }
}

// final layer: out(f32) = h @ Ws + agg @ Wn + b
__global__ __launch_bounds__(256) void gemm_final_mfma(const unsigned short* __restrict__ h,
                                                       const unsigned short* __restrict__ agg,
                                                       const unsigned short* __restrict__ wbs,
                                                       const unsigned short* __restrict__ wbn,
                                                       const float* __restrict__ b,
                                                       float* __restrict__ out) {
    int tid = threadIdx.x;
    int lane = tid & 63;
    int row0 = blockIdx.x * 64 + (tid >> 6) * 16;
    bf16x8 ah0, ah1, ag0, ag1;
    load_A(h, row0, lane, ah0, ah1);
    load_A(agg, row0, lane, ag0, ag1);
    const bf16x8* WS = (const bf16x8*)wbs;
    const bf16x8* WN = (const bf16x8*)wbn;
    f32x4 acc[4];
#pragma unroll
    for (int c = 0; c < 4; ++c) {
        float bv = b[c * 16 + (lane & 15)];
        acc[c] = f32x4{bv, bv, bv, bv};
        acc[c] = mfma16(ah0, WS[(0 * 4 + c) * 64 + lane], acc[c]);
        acc[c] = mfma16(ah1, WS[(1 * 4 + c) * 64 + lane], acc[c]);
        acc[c] = mfma16(ag0, WN[(0 * 4 + c) * 64 + lane], acc[c]);
        acc[c] = mfma16(ag1, WN[(1 * 4 + c) * 64 + lane], acc[c]);
    }
    int rbase = row0 + (lane >> 4) * 4;
#pragma unroll
    for (int reg = 0; reg < 4; ++reg) {
        int row = rbase + reg;
        if (row < NN) {
#pragma unroll
            for (int c = 0; c < 4; ++c)
                out[(size_t)row * DD + c * 16 + (lane & 15)] = acc[c][reg];
        }
    }
}

// ---------------- Aggregation: grid-stride, 2 nodes per wave (MLP x2) ----------------

__global__ __launch_bounds__(256) void agg_max(const unsigned short* __restrict__ z,
                                               const int* __restrict__ rowptr,
                                               const unsigned short* __restrict__ edge_src,
                                               unsigned short* __restrict__ agg, int n) {
    int wslot = __builtin_amdgcn_readfirstlane((int)((blockIdx.x * blockDim.x + threadIdx.x) >> 6));
    int nslots = (gridDim.x * blockDim.x) >> 6;
    int lane = threadIdx.x & 63;
    int eg = lane >> 3;            // edge slot (0..7)
    int fo = (lane & 7) * 8;       // feature offset (8 bf16 = 16B per lane)
    for (int nb = wslot * 2; nb < n; nb += nslots * 2) {
        int nA = nb;
        int nB = nb + 1;
        int begA = rowptr[nA], endA = rowptr[nA + 1];
        int begB = 0, endB = 0;
        if (nB < n) { begB = rowptr[nB]; endB = rowptr[nB + 1]; }
        unsigned int a0 = 0, a1 = 0, a2 = 0, a3 = 0;   // node A packed maxima
        unsigned int b0 = 0, b1 = 0, b2 = 0, b3 = 0;   // node B packed maxima
        int eA = begA + eg;
        int eB = begB + eg;
        // interleaved main loop: two independent gather chains in flight
        while (eA < endA && eB < endB) {
            int sA = edge_src[eA];
            int sB = edge_src[eB];
            uint4 vA = *(const uint4*)(z + (size_t)sA * DD + fo);
            uint4 vB = *(const uint4*)(z + (size_t)sB * DD + fo);
            a0 = pkmax(a0, vA.x); a1 = pkmax(a1, vA.y);
            a2 = pkmax(a2, vA.z); a3 = pkmax(a3, vA.w);
            b0 = pkmax(b0, vB.x); b1 = pkmax(b1, vB.y);
            b2 = pkmax(b2, vB.z); b3 = pkmax(b3, vB.w);
            eA += 8; eB += 8;
        }
        while (eA < endA) {
            int s = edge_src[eA];
            uint4 v = *(const uint4*)(z + (size_t)s * DD + fo);
            a0 = pkmax(a0, v.x); a1 = pkmax(a1, v.y);
            a2 = pkmax(a2, v.z); a3 = pkmax(a3, v.w);
            eA += 8;
        }
        while (eB < endB) {
            int s = edge_src[eB];
            uint4 v = *(const uint4*)(z + (size_t)s * DD + fo);
            b0 = pkmax(b0, v.x); b1 = pkmax(b1, v.y);
            b2 = pkmax(b2, v.z); b3 = pkmax(b3, v.w);
            eB += 8;
        }
        // reduce across the 8 edge slots (xor 8, 16, 32 in lane space)
#pragma unroll
        for (int o = 8; o < 64; o <<= 1) {
            a0 = pkmax(a0, (unsigned int)__shfl_xor((int)a0, o));
            a1 = pkmax(a1, (unsigned int)__shfl_xor((int)a1, o));
            a2 = pkmax(a2, (unsigned int)__shfl_xor((int)a2, o));
            a3 = pkmax(a3, (unsigned int)__shfl_xor((int)a3, o));
            b0 = pkmax(b0, (unsigned int)__shfl_xor((int)b0, o));
            b1 = pkmax(b1, (unsigned int)__shfl_xor((int)b1, o));
            b2 = pkmax(b2, (unsigned int)__shfl_xor((int)b2, o));
            b3 = pkmax(b3, (unsigned int)__shfl_xor((int)b3, o));
        }
        if (eg == 0) {
            uint4 o;
            o.x = a0; o.y = a1; o.z = a2; o.w = a3;
            *(uint4*)(agg + (size_t)nA * DD + fo) = o;
        } else if (eg == 1 && nB < n) {
            uint4 o;
            o.x = b0; o.y = b1; o.z = b2; o.w = b3;
            *(uint4*)(agg + (size_t)nB * DD + fo) = o;
        }
    }
}

// ---------------- Orchestration ----------------

extern "C" void kernel_launch(void* const* d_in, const int* in_sizes, int n_in,
                              void* d_out, int out_size, void* d_ws, size_t ws_size,
                              hipStream_t stream) {
    const float* in_feat = (const float*)d_in[0];
    const int* src = (const int*)d_in[1];
    const int* dst = (const int*)d_in[2];
    const float* W_pool = (const float*)d_in[3];
    const float* b_pool = (const float*)d_in[4];
    const float* W_self = (const float*)d_in[5];
    const float* W_neigh = (const float*)d_in[6];
    const float* bias = (const float*)d_in[7];
    float* out = (float*)d_out;

    char* ws = (char*)d_ws;
    size_t off = 0;
    auto alloc = [&](size_t bytes) -> void* {
        void* p = (void*)(ws + off);
        off += (bytes + 255) & ~(size_t)255;
        return p;
    };
    int* rowptr              = (int*)alloc((NN + 1) * sizeof(int));
    int* H                   = (int*)alloc((size_t)NB1 * NBLK1 * sizeof(int));
    int* rowsum              = (int*)alloc(NB1 * sizeof(int));
    int* colbase             = (int*)alloc((NB1 + 1) * sizeof(int));
    int* ticket              = (int*)alloc(sizeof(int));
    unsigned short* edge_src = (unsigned short*)alloc((size_t)NE * sizeof(unsigned short));
    unsigned short* z        = (unsigned short*)alloc((size_t)NN * DD * sizeof(unsigned short));
    unsigned short* agg      = (unsigned short*)alloc((size_t)NN * DD * sizeof(unsigned short));
    unsigned short* h0       = (unsigned short*)alloc((size_t)NN * DD * sizeof(unsigned short));
    unsigned short* h1       = (unsigned short*)alloc((size_t)NN * DD * sizeof(unsigned short));
    unsigned short* h2       = (unsigned short*)alloc((size_t)NN * DD * sizeof(unsigned short));
    unsigned short* wb       = (unsigned short*)alloc((size_t)NMAT * 512 * 8 * sizeof(unsigned short));
    int* pairs               = (int*)alloc((size_t)NE * sizeof(int));
    (void)ws_size; (void)in_sizes; (void)n_in; (void)out_size;

    hipMemsetAsync(ticket, 0, sizeof(int), stream);

    auto WBp = [&](int l) { return wb + (size_t)(0 + l) * 4096; };
    auto WBs = [&](int l) { return wb + (size_t)(3 + l) * 4096; };
    auto WBn = [&](int l) { return wb + (size_t)(6 + l) * 4096; };

    // ---- fat1: edge histogram | in_feat cast | weight reformat ----
    fat1<<<NBLK1 + CAST_BLOCKS + NMAT, 256, 0, stream>>>(
        dst, H, in_feat, h0, W_pool, W_self, W_neigh, wb);
    // ---- fat2: rowsum+scan | pool0 MFMA ----
    fat2<<<NB1 + GEMM_BLOCKS, 256, 0, stream>>>(
        H, rowsum, colbase, ticket, h0, wb, b_pool, z);
    // ---- CSR rest (p1/p2 at 512 threads for occupancy in barrier phases) ----
    k3_offsets<<<(NB1 * 64 + 255) / 256, 256, 0, stream>>>(H, colbase);
    p1_scatter<<<NBLK1, 512, 0, stream>>>(dst, src, H, pairs, NE);
    p2_bucket<<<NB1, 512, 0, stream>>>(pairs, colbase, rowptr, edge_src);

    // ---- 3 layers ----
    agg_max<<<2048, 256, 0, stream>>>(z, rowptr, edge_src, agg, NN);
    gemm_fused_mfma<<<GEMM_BLOCKS, 256, 0, stream>>>(
        h0, agg, WBs(0), WBn(0), WBp(1), bias, b_pool + DD, h1, z);
    agg_max<<<2048, 256, 0, stream>>>(z, rowptr, edge_src, agg, NN);
    gemm_fused_mfma<<<GEMM_BLOCKS, 256, 0, stream>>>(
        h1, agg, WBs(1), WBn(1), WBp(2), bias + DD, b_pool + 2 * DD, h2, z);
    agg_max<<<2048, 256, 0, stream>>>(z, rowptr, edge_src, agg, NN);
    gemm_final_mfma<<<GEMM_BLOCKS, 256, 0, stream>>>(
        h2, agg, WBs(2), WBn(2), bias + 2 * DD, out);
}